// Round 5
// baseline (25.429 us; speedup 1.0000x reference)
//
#include <hip/hip_runtime.h>

#define B 32
#define R 48
#define L 128
#define D 64

// ---------------- prep: pack X,T,M,PD into float4 obs[b,l,d] ----------------
__global__ __launch_bounds__(256) void alnn_prep(
    const float* __restrict__ X, const float* __restrict__ T,
    const float* __restrict__ M, const float* __restrict__ PD,
    float4* __restrict__ obs4)
{
    const int i = blockIdx.x * 256 + threadIdx.x;   // 0 .. B*L*D-1
    obs4[i] = make_float4(X[i], T[i], M[i], PD[i]);
}

// ---------------- quadrant-tiled partial kernel ----------------
// Block tile: TRB r's x TBB b's x (L/NS_) l's. 4 waves in a 2x2 (r,b) quadrant
// grid; each wave owns (TRB/2 x TBB/2) pairs for ALL the block's l's.
// Intra-block duplicate reads (each r-half read by 2 waves, each b-half by 2
// waves, same l, same CU) are served by L1. No cross-wave reduce needed.
template<int TRB, int TBB, int NS_, bool PACKED>
__global__ __launch_bounds__(256) void alnn_part1_q(
    const float* __restrict__ X, const float* __restrict__ T,
    const float* __restrict__ M, const float* __restrict__ PD,
    const float4* __restrict__ obs4,
    const float* __restrict__ alpha, const float* __restrict__ w_v,
    const float* __restrict__ w_t, const float* __restrict__ b_t,
    const float* __restrict__ ref_time, float* __restrict__ ws)
{
    constexpr int TRW = TRB / 2;          // r's per wave
    constexpr int TBW = TBB / 2;          // b's per wave
    constexpr int NBT = B / TBB;
    constexpr int LCH = L / NS_;          // l's per block (each wave does all)

    const int id   = blockIdx.x;
    const int s    = id % NS_;
    const int rest = id / NS_;
    const int bt   = rest % NBT;
    const int rt   = rest / NBT;

    const int d  = threadIdx.x & 63;
    const int ly = threadIdx.x >> 6;      // wave 0..3
    const int r0 = rt * TRB + (ly >> 1) * TRW;
    const int b0 = bt * TBB + (ly & 1) * TBW;

    float a_[TRW], rt_[TRW];
    #pragma unroll
    for (int r = 0; r < TRW; ++r) {
        a_[r]  = fmaxf(alpha[r0 + r], 0.0f);
        rt_[r] = ref_time[r0 + r];
    }

    float acc[TRW][TBW];
    #pragma unroll
    for (int r = 0; r < TRW; ++r)
        #pragma unroll
        for (int b = 0; b < TBW; ++b) acc[r][b] = 0.0f;

    const float4* __restrict__ w_t4 = reinterpret_cast<const float4*>(w_t);
    const int l0 = s * LCH;

    #pragma unroll
    for (int li = 0; li < LCH; ++li) {
        const int l = l0 + li;
        float4 wt[TRW]; float btv[TRW], wv[TRW];
        #pragma unroll
        for (int r = 0; r < TRW; ++r) {
            const int iw = ((r0 + r) * L + l) * D + d;
            wt[r]  = w_t4[iw];
            btv[r] = 4.0f * b_t[iw];
            wv[r]  = w_v[iw];
        }
        float xv[TBW], tv[TBW], mv[TBW], pv[TBW];
        #pragma unroll
        for (int b = 0; b < TBW; ++b) {
            const int ix = ((b0 + b) * L + l) * D + d;
            if (PACKED) {
                const float4 o = obs4[ix];
                xv[b] = o.x; tv[b] = o.y; mv[b] = o.z; pv[b] = o.w;
            } else {
                xv[b] = X[ix]; tv[b] = T[ix]; mv[b] = M[ix]; pv[b] = PD[ix];
            }
        }
        #pragma unroll
        for (int r = 0; r < TRW; ++r) {
            #pragma unroll
            for (int b = 0; b < TBW; ++b) {
                const float dist  = fabsf(tv[b] - rt_[r]);
                const float kern  = __expf(-a_[r] * dist);
                const float inten = fmaxf(xv[b] * kern, 0.0f);
                const float ssum  = fmaf(wt[r].x, xv[b],
                                    fmaf(wt[r].y, inten,
                                    fmaf(wt[r].z, mv[b],
                                    fmaf(wt[r].w, pv[b], btv[r]))));
                acc[r][b] = fmaf(wv[r], fmaxf(ssum, 0.0f), acc[r][b]);
            }
        }
    }

    // direct partial write: quadrants are disjoint in (r,b) -> no reduce
    #pragma unroll
    for (int r = 0; r < TRW; ++r)
        #pragma unroll
        for (int b = 0; b < TBW; ++b)
            ws[(((size_t)s * B + (b0 + b)) * R + (r0 + r)) * D + d] = acc[r][b];
}

// ---------------- finalize: sum NS_ partials + bias + relu ----------------
template<int NS_>
__global__ __launch_bounds__(256) void alnn_part2_t(
    const float* __restrict__ ws, const float* __restrict__ b_v,
    float* __restrict__ out)
{
    const int i = blockIdx.x * 256 + threadIdx.x;   // i = (b*R + r)*D + d
    const int d = i & 63;
    const int r = (i >> 6) % R;
    const int b = i / (R * D);
    float sum = 0.0f;
    #pragma unroll
    for (int s = 0; s < NS_; ++s)
        sum += ws[(((size_t)s * B + b) * R + r) * D + d];
    out[i] = fmaxf(sum + (float)L * b_v[r * D + d], 0.0f);
}

// ---------------- tier C: exact R3 structure (known 16.8 us) ----------------
template<int TR_, int TB_, int NS_>
__global__ __launch_bounds__(256) void alnn_part1_t(
    const float* __restrict__ X, const float* __restrict__ T,
    const float* __restrict__ M, const float* __restrict__ PD,
    const float* __restrict__ alpha, const float* __restrict__ w_v,
    const float* __restrict__ w_t, const float* __restrict__ b_t,
    const float* __restrict__ ref_time, float* __restrict__ ws)
{
    constexpr int NBT = B / TB_;
    constexpr int LCH = L / NS_;
    constexpr int LW  = LCH / 4;
    const int id   = blockIdx.x;
    const int s    = id % NS_;
    const int rest = id / NS_;
    const int bt   = rest % NBT;
    const int rt   = rest / NBT;
    const int d    = threadIdx.x & 63;
    const int ly   = threadIdx.x >> 6;
    const int r0 = rt * TR_, b0 = bt * TB_;

    float a_[TR_], rt_[TR_];
    #pragma unroll
    for (int r = 0; r < TR_; ++r) {
        a_[r]  = fmaxf(alpha[r0 + r], 0.0f);
        rt_[r] = ref_time[r0 + r];
    }
    float acc[TR_][TB_];
    #pragma unroll
    for (int r = 0; r < TR_; ++r)
        #pragma unroll
        for (int b = 0; b < TB_; ++b) acc[r][b] = 0.0f;

    const float4* __restrict__ w_t4 = reinterpret_cast<const float4*>(w_t);
    const int l0 = s * LCH + ly * LW;

    #pragma unroll
    for (int li = 0; li < LW; ++li) {
        const int l = l0 + li;
        float4 wt[TR_]; float btv[TR_], wv[TR_];
        #pragma unroll
        for (int r = 0; r < TR_; ++r) {
            const int iw = ((r0 + r) * L + l) * D + d;
            wt[r]  = w_t4[iw];
            btv[r] = 4.0f * b_t[iw];
            wv[r]  = w_v[iw];
        }
        float xv[TB_], tv[TB_], mv[TB_], pv[TB_];
        #pragma unroll
        for (int b = 0; b < TB_; ++b) {
            const int ix = ((b0 + b) * L + l) * D + d;
            xv[b] = X[ix];  tv[b] = T[ix];  mv[b] = M[ix];  pv[b] = PD[ix];
        }
        #pragma unroll
        for (int r = 0; r < TR_; ++r) {
            #pragma unroll
            for (int b = 0; b < TB_; ++b) {
                const float dist  = fabsf(tv[b] - rt_[r]);
                const float kern  = __expf(-a_[r] * dist);
                const float inten = fmaxf(xv[b] * kern, 0.0f);
                const float ssum  = fmaf(wt[r].x, xv[b],
                                    fmaf(wt[r].y, inten,
                                    fmaf(wt[r].z, mv[b],
                                    fmaf(wt[r].w, pv[b], btv[r]))));
                acc[r][b] = fmaf(wv[r], fmaxf(ssum, 0.0f), acc[r][b]);
            }
        }
    }

    __shared__ float red[4][TR_ * TB_][64];
    #pragma unroll
    for (int r = 0; r < TR_; ++r)
        #pragma unroll
        for (int b = 0; b < TB_; ++b)
            red[ly][r * TB_ + b][d] = acc[r][b];
    __syncthreads();
    #pragma unroll
    for (int p = ly; p < TR_ * TB_; p += 4) {
        const int r = p / TB_, b = p % TB_;
        const float v = red[0][p][d] + red[1][p][d] + red[2][p][d] + red[3][p][d];
        ws[(((size_t)s * B + (b0 + b)) * R + (r0 + r)) * D + d] = v;
    }
}

// ---------------- fallback (round-1 kernel) if ws too small ----------------
__global__ __launch_bounds__(256) void alnn_fallback(
    const float* __restrict__ X, const float* __restrict__ T,
    const float* __restrict__ M, const float* __restrict__ PD,
    const float* __restrict__ alpha, const float* __restrict__ w_v,
    const float* __restrict__ w_t, const float* __restrict__ b_t,
    const float* __restrict__ b_v, const float* __restrict__ ref_time,
    float* __restrict__ out)
{
    const int br = blockIdx.x;
    const int b  = br / R;
    const int r  = br - b * R;
    const int d  = threadIdx.x & 63;
    const int ly = threadIdx.x >> 6;

    const float a  = fmaxf(alpha[r], 0.0f);
    const float rt = ref_time[r];
    const int baseX = b * L * D + d;
    const int baseW = r * L * D + d;

    float acc = 0.0f;
    const int l0 = ly * 32;
    #pragma unroll 4
    for (int li = 0; li < 32; ++li) {
        const int l  = l0 + li;
        const int ix = baseX + l * D;
        const int iw = baseW + l * D;
        const float x  = X[ix], t = T[ix], m = M[ix], pd = PD[ix];
        const float dist  = fabsf(t - rt);
        const float kern  = __expf(-a * dist);
        const float inten = fmaxf(x * kern, 0.0f);
        const float4 wt = reinterpret_cast<const float4*>(w_t)[iw];
        const float bt  = b_t[iw];
        float s = fmaf(wt.x, x, fmaf(wt.y, inten, fmaf(wt.z, m, fmaf(wt.w, pd, 4.0f * bt))));
        acc = fmaf(w_v[iw], fmaxf(s, 0.0f), acc);
    }
    __shared__ float red[4][64];
    red[ly][d] = acc;
    __syncthreads();
    if (ly == 0) {
        const float sum = red[0][d] + red[1][d] + red[2][d] + red[3][d];
        out[(b * R + r) * D + d] = fmaxf(sum + (float)L * b_v[r * D + d], 0.0f);
    }
}

extern "C" void kernel_launch(void* const* d_in, const int* in_sizes, int n_in,
                              void* d_out, int out_size, void* d_ws, size_t ws_size,
                              hipStream_t stream) {
    const float* X  = (const float*)d_in[0];
    const float* T  = (const float*)d_in[1];
    const float* M  = (const float*)d_in[2];
    const float* PD = (const float*)d_in[3];
    const float* alpha = (const float*)d_in[4];
    const float* w_v   = (const float*)d_in[5];
    const float* w_t   = (const float*)d_in[6];
    const float* b_t   = (const float*)d_in[7];
    const float* b_v   = (const float*)d_in[8];
    const float* ref_time = (const float*)d_in[9];
    float* out = (float*)d_out;

    const size_t part_bytes = (size_t)32 * B * R * D * sizeof(float);  // 12.6 MB (NS=32)
    const size_t obs_bytes  = (size_t)B * L * D * 4 * sizeof(float);   // 4.2 MB
    const size_t ws16       = (size_t)16 * B * R * D * sizeof(float);  // 6.29 MB
    const size_t ws4        = (size_t)4  * B * R * D * sizeof(float);  // 1.57 MB

    // quadrant tier: TRB=6, TBB=8, NS=32 -> grid 8*4*32 = 1024
    if (ws_size >= part_bytes + obs_bytes) {
        float* ws   = (float*)d_ws;
        float4* obs = (float4*)((char*)d_ws + part_bytes);
        hipLaunchKernelGGL(alnn_prep, dim3(B * L * D / 256), dim3(256), 0, stream,
                           X, T, M, PD, obs);
        hipLaunchKernelGGL((alnn_part1_q<6, 8, 32, true>), dim3(1024), dim3(256), 0, stream,
                           X, T, M, PD, obs, alpha, w_v, w_t, b_t, ref_time, ws);
        hipLaunchKernelGGL((alnn_part2_t<32>), dim3(B * R * D / 256), dim3(256), 0, stream,
                           ws, b_v, out);
    } else if (ws_size >= part_bytes) {
        float* ws = (float*)d_ws;
        hipLaunchKernelGGL((alnn_part1_q<6, 8, 32, false>), dim3(1024), dim3(256), 0, stream,
                           X, T, M, PD, nullptr, alpha, w_v, w_t, b_t, ref_time, ws);
        hipLaunchKernelGGL((alnn_part2_t<32>), dim3(B * R * D / 256), dim3(256), 0, stream,
                           ws, b_v, out);
    } else if (ws_size >= ws16) {
        float* ws = (float*)d_ws;
        hipLaunchKernelGGL((alnn_part1_t<4, 4, 16>), dim3(1536), dim3(256), 0, stream,
                           X, T, M, PD, alpha, w_v, w_t, b_t, ref_time, ws);
        hipLaunchKernelGGL((alnn_part2_t<16>), dim3(B * R * D / 256), dim3(256), 0, stream,
                           ws, b_v, out);
    } else if (ws_size >= ws4) {
        float* ws = (float*)d_ws;
        hipLaunchKernelGGL((alnn_part1_t<2, 2, 4>), dim3(1536), dim3(256), 0, stream,
                           X, T, M, PD, alpha, w_v, w_t, b_t, ref_time, ws);
        hipLaunchKernelGGL((alnn_part2_t<4>), dim3(B * R * D / 256), dim3(256), 0, stream,
                           ws, b_v, out);
    } else {
        hipLaunchKernelGGL(alnn_fallback, dim3(B * R), dim3(256), 0, stream,
                           X, T, M, PD, alpha, w_v, w_t, b_t, b_v, ref_time, out);
    }
}

// Round 6
// 17.314 us; speedup vs baseline: 1.4687x; 1.4687x over previous
//
#include <hip/hip_runtime.h>

#define B 32
#define R 48
#define L 128
#define D 64

// ---------------- tiled partial kernel (R3 structure, occupancy-tuned) ----------------
// grid = (R/TR_)*(B/TB_)*NS_, block = 256 (4 waves; lane = d), MINW waves/EU.
// TR=3, TB=4, NS=16 -> 2048 blocks, 8 blocks/CU (32 waves/CU = HW max), VGPR<=64.
template<int TR_, int TB_, int NS_, int MINW>
__global__ __launch_bounds__(256, MINW) void alnn_part1_t(
    const float* __restrict__ X, const float* __restrict__ T,
    const float* __restrict__ M, const float* __restrict__ PD,
    const float* __restrict__ alpha, const float* __restrict__ w_v,
    const float* __restrict__ w_t, const float* __restrict__ b_t,
    const float* __restrict__ ref_time, float* __restrict__ ws)
{
    constexpr int NBT = B / TB_;
    constexpr int LCH = L / NS_;
    constexpr int LW  = LCH / 4;          // l-values per wave
    const int id   = blockIdx.x;
    const int s    = id % NS_;
    const int rest = id / NS_;
    const int bt   = rest % NBT;
    const int rt   = rest / NBT;
    const int d    = threadIdx.x & 63;
    const int ly   = threadIdx.x >> 6;    // wave 0..3
    const int r0 = rt * TR_, b0 = bt * TB_;

    float a_[TR_], rt_[TR_];
    #pragma unroll
    for (int r = 0; r < TR_; ++r) {
        a_[r]  = fmaxf(alpha[r0 + r], 0.0f);
        rt_[r] = ref_time[r0 + r];
    }

    float acc[TR_][TB_];
    #pragma unroll
    for (int r = 0; r < TR_; ++r)
        #pragma unroll
        for (int b = 0; b < TB_; ++b) acc[r][b] = 0.0f;

    const float4* __restrict__ w_t4 = reinterpret_cast<const float4*>(w_t);
    const int l0 = s * LCH + ly * LW;

    #pragma unroll
    for (int li = 0; li < LW; ++li) {
        const int l = l0 + li;
        float4 wt[TR_]; float btv[TR_], wv[TR_];
        #pragma unroll
        for (int r = 0; r < TR_; ++r) {
            const int iw = ((r0 + r) * L + l) * D + d;
            wt[r]  = w_t4[iw];
            btv[r] = 4.0f * b_t[iw];
            wv[r]  = w_v[iw];
        }
        float xv[TB_], tv[TB_], mv[TB_], pv[TB_];
        #pragma unroll
        for (int b = 0; b < TB_; ++b) {
            const int ix = ((b0 + b) * L + l) * D + d;
            xv[b] = X[ix];  tv[b] = T[ix];  mv[b] = M[ix];  pv[b] = PD[ix];
        }
        #pragma unroll
        for (int r = 0; r < TR_; ++r) {
            #pragma unroll
            for (int b = 0; b < TB_; ++b) {
                const float dist  = fabsf(tv[b] - rt_[r]);
                const float kern  = __expf(-a_[r] * dist);
                const float inten = fmaxf(xv[b] * kern, 0.0f);
                const float ssum  = fmaf(wt[r].x, xv[b],
                                    fmaf(wt[r].y, inten,
                                    fmaf(wt[r].z, mv[b],
                                    fmaf(wt[r].w, pv[b], btv[r]))));
                acc[r][b] = fmaf(wv[r], fmaxf(ssum, 0.0f), acc[r][b]);
            }
        }
    }

    __shared__ float red[4][TR_ * TB_][64];
    #pragma unroll
    for (int r = 0; r < TR_; ++r)
        #pragma unroll
        for (int b = 0; b < TB_; ++b)
            red[ly][r * TB_ + b][d] = acc[r][b];
    __syncthreads();

    #pragma unroll
    for (int p = ly; p < TR_ * TB_; p += 4) {
        const int r = p / TB_, b = p % TB_;
        const float v = red[0][p][d] + red[1][p][d] + red[2][p][d] + red[3][p][d];
        ws[(((size_t)s * B + (b0 + b)) * R + (r0 + r)) * D + d] = v;
    }
}

// ---------------- finalize: sum NS_ partials + bias + relu ----------------
template<int NS_>
__global__ __launch_bounds__(256) void alnn_part2_t(
    const float* __restrict__ ws, const float* __restrict__ b_v,
    float* __restrict__ out)
{
    const int i = blockIdx.x * 256 + threadIdx.x;   // i = (b*R + r)*D + d
    const int d = i & 63;
    const int r = (i >> 6) % R;
    const int b = i / (R * D);
    float sum = 0.0f;
    #pragma unroll
    for (int s = 0; s < NS_; ++s)
        sum += ws[(((size_t)s * B + b) * R + r) * D + d];
    out[i] = fmaxf(sum + (float)L * b_v[r * D + d], 0.0f);
}

// ---------------- fallback (round-1 kernel) if ws too small ----------------
__global__ __launch_bounds__(256) void alnn_fallback(
    const float* __restrict__ X, const float* __restrict__ T,
    const float* __restrict__ M, const float* __restrict__ PD,
    const float* __restrict__ alpha, const float* __restrict__ w_v,
    const float* __restrict__ w_t, const float* __restrict__ b_t,
    const float* __restrict__ b_v, const float* __restrict__ ref_time,
    float* __restrict__ out)
{
    const int br = blockIdx.x;
    const int b  = br / R;
    const int r  = br - b * R;
    const int d  = threadIdx.x & 63;
    const int ly = threadIdx.x >> 6;

    const float a  = fmaxf(alpha[r], 0.0f);
    const float rt = ref_time[r];
    const int baseX = b * L * D + d;
    const int baseW = r * L * D + d;

    float acc = 0.0f;
    const int l0 = ly * 32;
    #pragma unroll 4
    for (int li = 0; li < 32; ++li) {
        const int l  = l0 + li;
        const int ix = baseX + l * D;
        const int iw = baseW + l * D;
        const float x  = X[ix], t = T[ix], m = M[ix], pd = PD[ix];
        const float dist  = fabsf(t - rt);
        const float kern  = __expf(-a * dist);
        const float inten = fmaxf(x * kern, 0.0f);
        const float4 wt = reinterpret_cast<const float4*>(w_t)[iw];
        const float bt  = b_t[iw];
        float s = fmaf(wt.x, x, fmaf(wt.y, inten, fmaf(wt.z, m, fmaf(wt.w, pd, 4.0f * bt))));
        acc = fmaf(w_v[iw], fmaxf(s, 0.0f), acc);
    }
    __shared__ float red[4][64];
    red[ly][d] = acc;
    __syncthreads();
    if (ly == 0) {
        const float sum = red[0][d] + red[1][d] + red[2][d] + red[3][d];
        out[(b * R + r) * D + d] = fmaxf(sum + (float)L * b_v[r * D + d], 0.0f);
    }
}

extern "C" void kernel_launch(void* const* d_in, const int* in_sizes, int n_in,
                              void* d_out, int out_size, void* d_ws, size_t ws_size,
                              hipStream_t stream) {
    const float* X  = (const float*)d_in[0];
    const float* T  = (const float*)d_in[1];
    const float* M  = (const float*)d_in[2];
    const float* PD = (const float*)d_in[3];
    const float* alpha = (const float*)d_in[4];
    const float* w_v   = (const float*)d_in[5];
    const float* w_t   = (const float*)d_in[6];
    const float* b_t   = (const float*)d_in[7];
    const float* b_v   = (const float*)d_in[8];
    const float* ref_time = (const float*)d_in[9];
    float* out = (float*)d_out;
    float* ws  = (float*)d_ws;

    const size_t ws16 = (size_t)16 * B * R * D * sizeof(float);  // 6.29 MB
    const size_t ws4  = (size_t) 4 * B * R * D * sizeof(float);  // 1.57 MB

    if (ws_size >= ws16) {
        // TR=3,TB=4,NS=16: 16*8*16 = 2048 blocks, 8 blocks/CU (32 waves/CU max)
        hipLaunchKernelGGL((alnn_part1_t<3, 4, 16, 8>), dim3(2048), dim3(256), 0, stream,
                           X, T, M, PD, alpha, w_v, w_t, b_t, ref_time, ws);
        hipLaunchKernelGGL((alnn_part2_t<16>), dim3(B * R * D / 256), dim3(256), 0, stream,
                           ws, b_v, out);
    } else if (ws_size >= ws4) {
        hipLaunchKernelGGL((alnn_part1_t<2, 2, 4, 1>), dim3(1536), dim3(256), 0, stream,
                           X, T, M, PD, alpha, w_v, w_t, b_t, ref_time, ws);
        hipLaunchKernelGGL((alnn_part2_t<4>), dim3(B * R * D / 256), dim3(256), 0, stream,
                           ws, b_v, out);
    } else {
        hipLaunchKernelGGL(alnn_fallback, dim3(B * R), dim3(256), 0, stream,
                           X, T, M, PD, alpha, w_v, w_t, b_t, b_v, ref_time, out);
    }
}